// Round 1
// baseline (363.006 us; speedup 1.0000x reference)
//
#include <hip/hip_runtime.h>
#include <hip/hip_bf16.h>

#define T_TOK 4096
#define H_DIM 768
#define E_NUM 8
#define F_DIM 1536
#define BM 64
#define BN 64
#define LDT 48  // LDS row stride in ushorts (96B, 16B-aligned, conflict-reducing)

typedef __bf16 bf16x8 __attribute__((ext_vector_type(8)));
typedef unsigned short u16x8 __attribute__((ext_vector_type(8)));
typedef float f32x4 __attribute__((ext_vector_type(4)));

__device__ __forceinline__ unsigned short f2bf(float f) {
    unsigned int u = __float_as_uint(f);
    u += 0x7FFF + ((u >> 16) & 1);   // RNE
    return (unsigned short)(u >> 16);
}

// ---------------- fp32 -> bf16 convert ----------------
__global__ void convert_bf16_kernel(const float* __restrict__ src,
                                    unsigned short* __restrict__ dst, int n) {
    int i = (blockIdx.x * blockDim.x + threadIdx.x) * 4;
    int stride = gridDim.x * blockDim.x * 4;
    for (; i < n; i += stride) {
        float4 v = *reinterpret_cast<const float4*>(src + i);
        ushort4 o;
        o.x = f2bf(v.x); o.y = f2bf(v.y); o.z = f2bf(v.z); o.w = f2bf(v.w);
        *reinterpret_cast<ushort4*>(dst + i) = o;
    }
}

// ---------------- router: logits + top2 + lists ----------------
__global__ void router_kernel(const float* __restrict__ x,
                              const float* __restrict__ gw,
                              float* __restrict__ logits_out,
                              float* __restrict__ weight,
                              int* __restrict__ list,
                              int* __restrict__ counts) {
    int t = blockIdx.x;
    int lane = threadIdx.x;
    const float* xr = x + (size_t)t * H_DIM;
    float xv[12];
#pragma unroll
    for (int i = 0; i < 12; ++i) xv[i] = xr[lane + i * 64];
    float lg[E_NUM];
#pragma unroll
    for (int e = 0; e < E_NUM; ++e) {
        const float* g = gw + e * H_DIM;
        float p = 0.f;
#pragma unroll
        for (int i = 0; i < 12; ++i) p += xv[i] * g[lane + i * 64];
#pragma unroll
        for (int off = 32; off > 0; off >>= 1) p += __shfl_xor(p, off);
        lg[e] = p;
    }
    if (lane == 0) {
#pragma unroll
        for (int e = 0; e < E_NUM; ++e) logits_out[t * E_NUM + e] = lg[e];
        int e0 = 0; float m0 = lg[0];
#pragma unroll
        for (int e = 1; e < E_NUM; ++e) if (lg[e] > m0) { m0 = lg[e]; e0 = e; }
        int e1 = -1; float m1 = -1e30f;
#pragma unroll
        for (int e = 0; e < E_NUM; ++e) {
            if (e == e0) continue;
            if (lg[e] > m1) { m1 = lg[e]; e1 = e; }
        }
        // renormalized top-2 weights; softmax Z cancels
        float z1 = __expf(m1 - m0);
        float w0 = 1.f / (1.f + z1);
        weight[t * 2 + 0] = w0;
        weight[t * 2 + 1] = 1.f - w0;
        int p0 = atomicAdd(&counts[e0], 1);
        list[e0 * T_TOK + p0] = t * 2;
        int p1 = atomicAdd(&counts[e1], 1);
        list[e1 * T_TOK + p1] = t * 2 + 1;
    }
}

// ---------------- GEMM 1&3 fused: act = silu(X w1^T) * (X w3^T) ----------------
__global__ __launch_bounds__(256) void gemm13_kernel(
    const unsigned short* __restrict__ xb,
    const unsigned short* __restrict__ w1b,
    const unsigned short* __restrict__ w3b,
    const int* __restrict__ list,
    const int* __restrict__ counts,
    unsigned short* __restrict__ act) {
    int e = blockIdx.z;
    int cnt = counts[e];
    int tm = blockIdx.x;
    if (tm * BM >= cnt) return;
    int tn = blockIdx.y;
    const int* lst = list + e * T_TOK + tm * BM;

    __shared__ unsigned short sA[BM * LDT];
    __shared__ unsigned short sB1[BN * LDT];
    __shared__ unsigned short sB3[BN * LDT];

    int tid = threadIdx.x;
    int lane = tid & 63;
    int wid = tid >> 6;
    int waveM = (wid >> 1) * 32;
    int waveN = (wid & 1) * 32;

    int lr = tid >> 2;         // staging row 0..63
    int lc = (tid & 3) * 8;    // staging col chunk

    int aidx = tm * BM + lr;
    int arow = -1;
    if (aidx < cnt) arow = lst[lr] >> 1;   // token index
    const unsigned short* xr = (arow >= 0) ? xb + (size_t)arow * H_DIM : xb;
    const unsigned short* w1r = w1b + ((size_t)e * F_DIM + (size_t)tn * BN + lr) * H_DIM;
    const unsigned short* w3r = w3b + ((size_t)e * F_DIM + (size_t)tn * BN + lr) * H_DIM;

    f32x4 accG[2][2] = {};
    f32x4 accU[2][2] = {};

    for (int kt = 0; kt < H_DIM; kt += 32) {
        u16x8 av = {0, 0, 0, 0, 0, 0, 0, 0};
        if (arow >= 0) av = *reinterpret_cast<const u16x8*>(xr + kt + lc);
        u16x8 b1v = *reinterpret_cast<const u16x8*>(w1r + kt + lc);
        u16x8 b3v = *reinterpret_cast<const u16x8*>(w3r + kt + lc);
        *reinterpret_cast<u16x8*>(&sA[lr * LDT + lc]) = av;
        *reinterpret_cast<u16x8*>(&sB1[lr * LDT + lc]) = b1v;
        *reinterpret_cast<u16x8*>(&sB3[lr * LDT + lc]) = b3v;
        __syncthreads();
        int kb = (lane >> 4) * 8;
        int rA = lane & 15;
#pragma unroll
        for (int mi = 0; mi < 2; ++mi) {
            bf16x8 a = *reinterpret_cast<const bf16x8*>(&sA[(waveM + mi * 16 + rA) * LDT + kb]);
#pragma unroll
            for (int ni = 0; ni < 2; ++ni) {
                bf16x8 b1 = *reinterpret_cast<const bf16x8*>(&sB1[(waveN + ni * 16 + rA) * LDT + kb]);
                bf16x8 b3 = *reinterpret_cast<const bf16x8*>(&sB3[(waveN + ni * 16 + rA) * LDT + kb]);
                accG[mi][ni] = __builtin_amdgcn_mfma_f32_16x16x32_bf16(a, b1, accG[mi][ni], 0, 0, 0);
                accU[mi][ni] = __builtin_amdgcn_mfma_f32_16x16x32_bf16(a, b3, accU[mi][ni], 0, 0, 0);
            }
        }
        __syncthreads();
    }

    int rowGrp = (lane >> 4) * 4;
    int colIn = lane & 15;
#pragma unroll
    for (int mi = 0; mi < 2; ++mi) {
#pragma unroll
        for (int r = 0; r < 4; ++r) {
            int m = waveM + mi * 16 + rowGrp + r;
            int midx = tm * BM + m;
            if (midx >= cnt) continue;
            int entry = lst[m];
            size_t rowOff = (size_t)entry * F_DIM + (size_t)tn * BN;
#pragma unroll
            for (int ni = 0; ni < 2; ++ni) {
                float g = accG[mi][ni][r];
                float u = accU[mi][ni][r];
                float s = g / (1.f + __expf(-g));   // silu
                act[rowOff + waveN + ni * 16 + colIn] = f2bf(s * u);
            }
        }
    }
}

// ---------------- GEMM 2: ybuf = (act w2^T) * route_weight ----------------
__global__ __launch_bounds__(256) void gemm2_kernel(
    const unsigned short* __restrict__ act,
    const unsigned short* __restrict__ w2b,
    const int* __restrict__ list,
    const int* __restrict__ counts,
    const float* __restrict__ weight,
    float* __restrict__ ybuf) {
    int e = blockIdx.z;
    int cnt = counts[e];
    int tm = blockIdx.x;
    if (tm * BM >= cnt) return;
    int tn = blockIdx.y;
    const int* lst = list + e * T_TOK + tm * BM;

    __shared__ unsigned short sA[BM * LDT];
    __shared__ unsigned short sB[BN * LDT];

    int tid = threadIdx.x;
    int lane = tid & 63;
    int wid = tid >> 6;
    int waveM = (wid >> 1) * 32;
    int waveN = (wid & 1) * 32;

    int lr = tid >> 2;
    int lc = (tid & 3) * 8;

    int aidx = tm * BM + lr;
    int arow = -1;
    if (aidx < cnt) arow = lst[lr];        // act row = t*2+slot
    const unsigned short* ar = (arow >= 0) ? act + (size_t)arow * F_DIM : act;
    const unsigned short* w2r = w2b + ((size_t)e * H_DIM + (size_t)tn * BN + lr) * F_DIM;

    f32x4 acc[2][2] = {};

    for (int kt = 0; kt < F_DIM; kt += 32) {
        u16x8 av = {0, 0, 0, 0, 0, 0, 0, 0};
        if (arow >= 0) av = *reinterpret_cast<const u16x8*>(ar + kt + lc);
        u16x8 bv = *reinterpret_cast<const u16x8*>(w2r + kt + lc);
        *reinterpret_cast<u16x8*>(&sA[lr * LDT + lc]) = av;
        *reinterpret_cast<u16x8*>(&sB[lr * LDT + lc]) = bv;
        __syncthreads();
        int kb = (lane >> 4) * 8;
        int rA = lane & 15;
#pragma unroll
        for (int mi = 0; mi < 2; ++mi) {
            bf16x8 a = *reinterpret_cast<const bf16x8*>(&sA[(waveM + mi * 16 + rA) * LDT + kb]);
#pragma unroll
            for (int ni = 0; ni < 2; ++ni) {
                bf16x8 b = *reinterpret_cast<const bf16x8*>(&sB[(waveN + ni * 16 + rA) * LDT + kb]);
                acc[mi][ni] = __builtin_amdgcn_mfma_f32_16x16x32_bf16(a, b, acc[mi][ni], 0, 0, 0);
            }
        }
        __syncthreads();
    }

    int rowGrp = (lane >> 4) * 4;
    int colIn = lane & 15;
#pragma unroll
    for (int mi = 0; mi < 2; ++mi) {
#pragma unroll
        for (int r = 0; r < 4; ++r) {
            int m = waveM + mi * 16 + rowGrp + r;
            int midx = tm * BM + m;
            if (midx >= cnt) continue;
            int entry = lst[m];
            float wv = weight[entry];
            size_t rowOff = (size_t)entry * H_DIM + (size_t)tn * BN;
#pragma unroll
            for (int ni = 0; ni < 2; ++ni) {
                ybuf[rowOff + waveN + ni * 16 + colIn] = acc[mi][ni][r] * wv;
            }
        }
    }
}

// ---------------- combine: y[t] = ybuf[2t] + ybuf[2t+1] ----------------
__global__ void combine_kernel(const float* __restrict__ ybuf, float* __restrict__ y) {
    int v = blockIdx.x * blockDim.x + threadIdx.x;   // over T*H/4
    if (v >= T_TOK * H_DIM / 4) return;
    int t = v / (H_DIM / 4);
    int hv = v % (H_DIM / 4);
    float4 a = reinterpret_cast<const float4*>(ybuf + (size_t)(2 * t) * H_DIM)[hv];
    float4 b = reinterpret_cast<const float4*>(ybuf + (size_t)(2 * t + 1) * H_DIM)[hv];
    float4 r;
    r.x = a.x + b.x; r.y = a.y + b.y; r.z = a.z + b.z; r.w = a.w + b.w;
    reinterpret_cast<float4*>(y)[v] = r;
}

extern "C" void kernel_launch(void* const* d_in, const int* in_sizes, int n_in,
                              void* d_out, int out_size, void* d_ws, size_t ws_size,
                              hipStream_t stream) {
    const float* x  = (const float*)d_in[0];
    const float* gw = (const float*)d_in[1];
    const float* w1 = (const float*)d_in[2];
    const float* w3 = (const float*)d_in[3];
    const float* w2 = (const float*)d_in[4];
    // d_in[5] = k (always 2)

    float* y = (float*)d_out;
    float* logits_out = y + (size_t)T_TOK * H_DIM;

    char* ws = (char*)d_ws;
    size_t off = 0;
    auto alloc = [&](size_t bytes) -> char* {
        char* p = ws + off;
        off += (bytes + 255) & ~(size_t)255;
        return p;
    };
    unsigned short* xb  = (unsigned short*)alloc((size_t)T_TOK * H_DIM * 2);
    unsigned short* w1b = (unsigned short*)alloc((size_t)E_NUM * F_DIM * H_DIM * 2);
    unsigned short* w3b = (unsigned short*)alloc((size_t)E_NUM * F_DIM * H_DIM * 2);
    unsigned short* w2b = (unsigned short*)alloc((size_t)E_NUM * H_DIM * F_DIM * 2);
    unsigned short* act = (unsigned short*)alloc((size_t)T_TOK * 2 * F_DIM * 2);
    float* ybuf   = (float*)alloc((size_t)T_TOK * 2 * H_DIM * 4);
    float* weight = (float*)alloc((size_t)T_TOK * 2 * 4);
    int* list     = (int*)alloc((size_t)E_NUM * T_TOK * 4);
    int* counts   = (int*)alloc((size_t)E_NUM * 4);

    hipMemsetAsync(counts, 0, E_NUM * sizeof(int), stream);

    // converts
    convert_bf16_kernel<<<1024, 256, 0, stream>>>(x, xb, T_TOK * H_DIM);
    convert_bf16_kernel<<<2048, 256, 0, stream>>>(w1, w1b, E_NUM * F_DIM * H_DIM);
    convert_bf16_kernel<<<2048, 256, 0, stream>>>(w3, w3b, E_NUM * F_DIM * H_DIM);
    convert_bf16_kernel<<<2048, 256, 0, stream>>>(w2, w2b, E_NUM * H_DIM * F_DIM);

    router_kernel<<<T_TOK, 64, 0, stream>>>(x, gw, logits_out, weight, list, counts);

    gemm13_kernel<<<dim3(T_TOK / BM, F_DIM / BN, E_NUM), 256, 0, stream>>>(
        xb, w1b, w3b, list, counts, act);

    gemm2_kernel<<<dim3(T_TOK / BM, H_DIM / BN, E_NUM), 256, 0, stream>>>(
        act, w2b, list, counts, weight, ybuf);

    combine_kernel<<<(T_TOK * H_DIM / 4 + 255) / 256, 256, 0, stream>>>(ybuf, y);
}